// Round 14
// baseline (305.290 us; speedup 1.0000x reference)
//
#include <hip/hip_runtime.h>
#include <hip/hip_bf16.h>

// Problem constants
#define DM     128
#define DSTATE 16
#define DINNER 256
#define CCONV  16
#define NEIGH  27
#define DSEQ   432   // CCONV * NEIGH
#define DTRANK 14
#define LVOL   4096  // 16*16*16
#define BATCH  2
#define NTOK   8192  // BATCH * LVOL

typedef __attribute__((ext_vector_type(8))) unsigned short ushort8_t;

__device__ __forceinline__ float bf2f(unsigned short u) {
    union { unsigned int i; float f; } v; v.i = ((unsigned int)u) << 16; return v.f;
}

// ---------------------------------------------------------------- merged weight prep
__global__ void k_wprep(const float* __restrict__ w_in, const float* __restrict__ w_fold,
                        const float* __restrict__ w_out, float2* __restrict__ wint2,
                        float* __restrict__ wft2, float* __restrict__ wot2) {
    int idx = blockIdx.x * 256 + threadIdx.x;
    if (idx < 32768) {
        int j = idx >> 8, t = idx & 255;
        wint2[idx] = make_float2(w_in[t * 128 + j], w_in[(t + 256) * 128 + j]);
    } else if (idx < 32768 + 110592) {
        int local = idx - 32768;
        int t = local / 432, d = local - t * 432;
        wft2[(d >> 1) * 512 + t * 2 + (d & 1)] = w_fold[t * 432 + d];
    } else if (idx < 32768 + 110592 + 32768) {
        int local = idx - 32768 - 110592;
        int o = local >> 8, i = local & 255;
        wot2[(i >> 1) * 256 + o * 2 + (i & 1)] = w_out[o * 256 + i];
    }
}

// ---------------------------------------------------------------- in-proj GEMM
__global__ void k_inproj(const float* __restrict__ x, const float2* __restrict__ wint2,
                         float* __restrict__ xpt, float* __restrict__ zbuf) {
    int t = threadIdx.x;
    int tokbase = blockIdx.x * 16;
    int b = tokbase >> 12, lb = tokbase & 4095;
    __shared__ float xs_[16][128];
    for (int idx = t; idx < 2048; idx += 256)
        xs_[idx >> 7][idx & 127] = x[tokbase * 128 + idx];
    __syncthreads();
    float a0[16], a1[16];
#pragma unroll
    for (int k = 0; k < 16; k++) { a0[k] = 0.f; a1[k] = 0.f; }
    for (int j = 0; j < 128; j += 4) {
        float2 w0 = wint2[(j + 0) * 256 + t];
        float2 w1 = wint2[(j + 1) * 256 + t];
        float2 w2 = wint2[(j + 2) * 256 + t];
        float2 w3 = wint2[(j + 3) * 256 + t];
#pragma unroll
        for (int k = 0; k < 16; k++) {
            float4 xv = *(const float4*)&xs_[k][j];
            a0[k] += xv.x * w0.x + xv.y * w1.x + xv.z * w2.x + xv.w * w3.x;
            a1[k] += xv.x * w0.y + xv.y * w1.y + xv.z * w2.y + xv.w * w3.y;
        }
    }
    float* xr = xpt + (size_t)(b * 256 + t) * 4096 + lb;
#pragma unroll
    for (int k = 0; k < 16; k++) xr[k] = a0[k];
#pragma unroll
    for (int k = 0; k < 16; k++) zbuf[(tokbase + k) * 256 + t] = a1[k];
}

// ---------------------------------------------------------------- grouped conv3d + SiLU
__global__ void k_conv(const float* __restrict__ xpt, const float* __restrict__ conv_w,
                       const float* __restrict__ conv_b, float* __restrict__ xc) {
    int t = threadIdx.x;
    int tok = blockIdx.x * 256 + t;
    int co = blockIdx.y;
    int b = tok >> 12, l = tok & 4095;
    int d0 = l >> 8, h0 = (l >> 4) & 15, w0 = l & 15;
    __shared__ float wl[432];
    for (int i = t; i < 432; i += 256) wl[i] = conv_w[co * 432 + i];  // [q][27]
    __syncthreads();
    int nbo[27];
#pragma unroll
    for (int t27 = 0; t27 < 27; t27++) {
        int di = t27 / 9 - 1, dj = (t27 / 3) % 3 - 1, dk = t27 % 3 - 1;
        int zd = d0 + di, zh = h0 + dj, zw = w0 + dk;
        nbo[t27] = ((unsigned)zd > 15u || (unsigned)zh > 15u || (unsigned)zw > 15u)
                   ? -1 : ((zd << 8) + (zh << 4) + zw);
    }
    const float* xb = xpt + (size_t)(b * 256 + co * 16) * 4096;
    float acc0 = conv_b[co], acc1 = 0.f;
    for (int t27 = 0; t27 < 27; t27++) {
        int o = nbo[t27];
        if (o >= 0) {
#pragma unroll
            for (int q = 0; q < 16; q += 2) {
                acc0 += xb[q * 4096 + o]       * wl[q * 27 + t27];
                acc1 += xb[(q + 1) * 4096 + o] * wl[(q + 1) * 27 + t27];
            }
        }
    }
    float acc = acc0 + acc1;
    acc = acc / (1.f + __expf(-acc));  // SiLU
    xc[(b * 16 + co) * 4096 + l] = acc;
}

// ---------------------------------------------------------------- x_dbl = x_proj_w @ unfold(xc)
// TWO channels per block (c, c+23): gather shared, two LDS weight rows.
__global__ void k_xdbl(const float* __restrict__ xc, const float* __restrict__ x_proj_w,
                       float* __restrict__ dts, __hip_bfloat16* __restrict__ bc2) {
    int t = threadIdx.x;
    int tok = blockIdx.x * 256 + t;
    int c0 = blockIdx.y;          // 0..22
    int c1 = c0 + 23;             // 23..45
    int b = tok >> 12, l = tok & 4095;
    int d0 = l >> 8, h0 = (l >> 4) & 15, w0 = l & 15;
    __shared__ float wl0[432], wl1[432];
    for (int i = t; i < 432; i += 256) {
        wl0[i] = x_proj_w[c0 * 432 + i];
        wl1[i] = x_proj_w[c1 * 432 + i];
    }
    __syncthreads();
    int nbo[27];
#pragma unroll
    for (int t27 = 0; t27 < 27; t27++) {
        int di = t27 / 9 - 1, dj = (t27 / 3) % 3 - 1, dk = t27 % 3 - 1;
        int zd = d0 + di, zh = h0 + dj, zw = w0 + dk;
        nbo[t27] = ((unsigned)zd > 15u || (unsigned)zh > 15u || (unsigned)zw > 15u)
                   ? -1 : ((zd << 8) + (zh << 4) + zw);
    }
    const float* xcb = xc + b * 16 * 4096;
    float a00 = 0.f, a01 = 0.f, a10 = 0.f, a11 = 0.f;
    for (int t27 = 0; t27 < 27; t27++) {
        int o = nbo[t27];
        if (o >= 0) {
#pragma unroll
            for (int ch = 0; ch < 16; ch += 2) {
                float v0 = xcb[ch * 4096 + o];
                float v1 = xcb[(ch + 1) * 4096 + o];
                int i0 = ch * 27 + t27, i1 = (ch + 1) * 27 + t27;
                a00 += v0 * wl0[i0];
                a01 += v1 * wl0[i1];
                a10 += v0 * wl1[i0];
                a11 += v1 * wl1[i1];
            }
        }
    }
    float acc0 = a00 + a01;
    float acc1 = a10 + a11;
    if (c0 < 14)
        dts[(size_t)(b * 14 + c0) * 4096 + l] = acc0;
    else
        bc2[(size_t)(b * 32 + (c0 - 14)) * 4096 + l] = __float2bfloat16(acc0);
    bc2[(size_t)(b * 32 + (c1 - 14)) * 4096 + l] = __float2bfloat16(acc1);
}

// ---------------------------------------------------------------- selective scan (+ fused delta)
// One block (256 thr) per (b, d-channel); thread t owns l in [t*16, t*16+16)
// (one full w-row). 864 blocks x 4 blocks/CU -> ALL co-resident (no tail round).
// Register discipline: dtv freed after av/dtu/sAll; Ap closed-form; Dskip*u
// applied at store via u reload. A[n]=-(n+1) fast path, exact fallback kept.
__global__ __launch_bounds__(256, 4) void k_scan(
        const float* __restrict__ xc, const float* __restrict__ dts,
        const unsigned short* __restrict__ bc2, const float* __restrict__ dt_w,
        const float* __restrict__ dt_b, const float* __restrict__ A_logs,
        const float* __restrict__ Ds, float* __restrict__ y) {
    int bd = blockIdx.x;
    int b = bd / 432, dch = bd % 432;
    int t = threadIdx.x;               // 0..255
    int lane = t & 63, wv = t >> 6;    // 4 waves

    bool intA = true;
#pragma unroll
    for (int n = 0; n < 16; n++) {
        float An = -__expf(A_logs[dch * 16 + n]);
        intA = intA && (fabsf(An + (float)(n + 1)) < 1e-3f);
    }
    float Dskip = Ds[dch];

    int cch = dch / 27, t27 = dch % 27;
    int di = t27 / 9 - 1, dj = (t27 / 3) % 3 - 1, dk = t27 % 3 - 1;

    // ---- fused delta -> dtv[16]
    float dtv[16];
    {
        float bias = dt_b[dch];
#pragma unroll
        for (int i = 0; i < 16; i++) dtv[i] = bias;
        const float* dsb = dts + (size_t)(b * 14) * 4096 + t * 16;
#pragma unroll
        for (int r = 0; r < 14; r++) {
            float w = dt_w[dch * 14 + r];
            const float4* dp = (const float4*)(dsb + (size_t)r * 4096);
#pragma unroll
            for (int q = 0; q < 4; q++) {
                float4 d4 = dp[q];
                dtv[4 * q + 0] += d4.x * w;
                dtv[4 * q + 1] += d4.y * w;
                dtv[4 * q + 2] += d4.z * w;
                dtv[4 * q + 3] += d4.w * w;
            }
        }
#pragma unroll
        for (int i = 0; i < 16; i++)
            dtv[i] = (dtv[i] > 15.f) ? dtv[i] : log1pf(__expf(dtv[i]));
    }

    // ---- u gather (one w-row), dtu; av = exp(-dt) [intA] or dt*log2e [fallback]
    int zd = (t >> 4) + di, zh = (t & 15) + dj;
    bool rowok = ((unsigned)zd <= 15u) && ((unsigned)zh <= 15u);
    const float* xr = xc + (size_t)(b * 16 + cch) * 4096 + (zd << 8) + (zh << 4);
    float dtu[16], av[16];
#pragma unroll
    for (int i = 0; i < 16; i++) {
        int zw = i + dk;
        float u = (rowok && (unsigned)zw <= 15u) ? xr[zw] : 0.f;
        dtu[i] = dtv[i] * u;
    }
    float sAll = 0.f;
#pragma unroll
    for (int i = 0; i < 16; i++) sAll += dtv[i];
    if (intA) {
#pragma unroll
        for (int i = 0; i < 16; i++) av[i] = __expf(-dtv[i]);
    } else {
#pragma unroll
        for (int i = 0; i < 16; i++) av[i] = dtv[i] * 1.44269504f;  // log2(e^dt)
    }
    // dtv dead from here

    const unsigned short* bcb = bc2 + (size_t)(b * 32) * 4096 + t * 16;

    // ---- pass 1: chunk transform (Ap, Bp); n-outer, row loads 2x ushort8
    float Ap[16], Bp[16];
    if (intA) {
        float aw[16];
#pragma unroll
        for (int i = 0; i < 16; i++) aw[i] = av[i];
        float P = __expf(-sAll);
        float ApAcc = P;
#pragma unroll
        for (int n = 0; n < 16; n++) {
            ushort8_t B0 = *(const ushort8_t*)(bcb + (size_t)n * 4096);
            ushort8_t B1 = *(const ushort8_t*)(bcb + (size_t)n * 4096 + 8);
            float bp = 0.f;
#pragma unroll
            for (int i = 0; i < 8; i++)
                bp = aw[i] * bp + dtu[i] * bf2f(B0[i]);
#pragma unroll
            for (int i = 8; i < 16; i++)
                bp = aw[i] * bp + dtu[i] * bf2f(B1[i - 8]);
            Ap[n] = ApAcc; Bp[n] = bp;
            if (n < 15) {
#pragma unroll
                for (int i = 0; i < 16; i++) aw[i] *= av[i];
                ApAcc *= P;
            }
        }
    } else {
        float s2 = sAll * 1.44269504f;
#pragma unroll
        for (int n = 0; n < 16; n++) {
            float An = -__expf(A_logs[dch * 16 + n]);
            ushort8_t B0 = *(const ushort8_t*)(bcb + (size_t)n * 4096);
            ushort8_t B1 = *(const ushort8_t*)(bcb + (size_t)n * 4096 + 8);
            float bp = 0.f;
#pragma unroll
            for (int i = 0; i < 8; i++) {
                float a = exp2f(av[i] * An);
                bp = a * bp + dtu[i] * bf2f(B0[i]);
            }
#pragma unroll
            for (int i = 8; i < 16; i++) {
                float a = exp2f(av[i] * An);
                bp = a * bp + dtu[i] * bf2f(B1[i - 8]);
            }
            Ap[n] = exp2f(s2 * An);
            Bp[n] = bp;
        }
    }

    // ---- wave-level inclusive scan (Hillis-Steele over 64 lanes)
#pragma unroll
    for (int s = 1; s < 64; s <<= 1) {
#pragma unroll
        for (int n = 0; n < 16; n++) {
            float pa = __shfl_up(Ap[n], s, 64);
            float pb = __shfl_up(Bp[n], s, 64);
            if (lane >= s) {
                Bp[n] = Ap[n] * pb + Bp[n];   // combine(earlier=(pa,pb), later)
                Ap[n] *= pa;
            }
        }
    }

    // ---- cross-wave prefix via tiny LDS (4 waves)
    __shared__ float waggA[4][16], waggB[4][16];
    if (lane == 63) {
#pragma unroll
        for (int n = 0; n < 16; n++) { waggA[wv][n] = Ap[n]; waggB[wv][n] = Bp[n]; }
    }
    __syncthreads();

    float h[16];
#pragma unroll
    for (int n = 0; n < 16; n++) {
        float exA = __shfl_up(Ap[n], 1, 64);
        float exB = __shfl_up(Bp[n], 1, 64);
        if (lane == 0) { exA = 1.f; exB = 0.f; }
        float WB = 0.f;
        for (int ww = 0; ww < wv; ww++)
            WB = waggA[ww][n] * WB + waggB[ww][n];
        h[n] = exA * WB + exB;     // incoming state for this chunk
    }

    // ---- pass 2: rescan with incoming state; ys accumulators (Dskip at store)
    float ys[16];
#pragma unroll
    for (int i = 0; i < 16; i++) ys[i] = 0.f;
    if (intA) {
        float aw[16];
#pragma unroll
        for (int i = 0; i < 16; i++) aw[i] = av[i];
#pragma unroll
        for (int n = 0; n < 16; n++) {
            ushort8_t B0 = *(const ushort8_t*)(bcb + (size_t)n * 4096);
            ushort8_t B1 = *(const ushort8_t*)(bcb + (size_t)n * 4096 + 8);
            ushort8_t C0 = *(const ushort8_t*)(bcb + (size_t)(16 + n) * 4096);
            ushort8_t C1 = *(const ushort8_t*)(bcb + (size_t)(16 + n) * 4096 + 8);
            float hn = h[n];
#pragma unroll
            for (int i = 0; i < 8; i++) {
                hn = aw[i] * hn + dtu[i] * bf2f(B0[i]);
                ys[i] += hn * bf2f(C0[i]);
            }
#pragma unroll
            for (int i = 8; i < 16; i++) {
                hn = aw[i] * hn + dtu[i] * bf2f(B1[i - 8]);
                ys[i] += hn * bf2f(C1[i - 8]);
            }
            if (n < 15) {
#pragma unroll
                for (int i = 0; i < 16; i++) aw[i] *= av[i];
            }
        }
    } else {
#pragma unroll
        for (int n = 0; n < 16; n++) {
            float An = -__expf(A_logs[dch * 16 + n]);
            ushort8_t B0 = *(const ushort8_t*)(bcb + (size_t)n * 4096);
            ushort8_t B1 = *(const ushort8_t*)(bcb + (size_t)n * 4096 + 8);
            ushort8_t C0 = *(const ushort8_t*)(bcb + (size_t)(16 + n) * 4096);
            ushort8_t C1 = *(const ushort8_t*)(bcb + (size_t)(16 + n) * 4096 + 8);
            float hn = h[n];
#pragma unroll
            for (int i = 0; i < 8; i++) {
                float a = exp2f(av[i] * An);
                hn = a * hn + dtu[i] * bf2f(B0[i]);
                ys[i] += hn * bf2f(C0[i]);
            }
#pragma unroll
            for (int i = 8; i < 16; i++) {
                float a = exp2f(av[i] * An);
                hn = a * hn + dtu[i] * bf2f(B1[i - 8]);
                ys[i] += hn * bf2f(C1[i - 8]);
            }
        }
    }

    // ---- store: reload u, add D-skip, 4x float4
    float o16[16];
#pragma unroll
    for (int i = 0; i < 16; i++) {
        int zw = i + dk;
        float u = (rowok && (unsigned)zw <= 15u) ? xr[zw] : 0.f;
        o16[i] = ys[i] + Dskip * u;
    }
    float* yo = y + (size_t)(b * 432 + dch) * 4096 + t * 16;
#pragma unroll
    for (int q = 0; q < 4; q++)
        *(float4*)(yo + 4 * q) = *(float4*)&o16[4 * q];
}

// ---------------------------------------------------------------- fold GEMM + LN + gate + out GEMM
__global__ void k_tail(const float* __restrict__ y, const float* __restrict__ zbuf,
                       const float2* __restrict__ wft2, const float* __restrict__ ln_g,
                       const float* __restrict__ ln_b, const float2* __restrict__ wot2,
                       float* __restrict__ out) {
    int t = threadIdx.x;
    int tokbase = blockIdx.x * 16;
    int b = tokbase >> 12, lbase = tokbase & 4095;
    __shared__ float ys[432][16];
    __shared__ float vs[256][20];
    __shared__ float mu_s[16], rs_s[16];

    for (int idx = t; idx < 432 * 16; idx += 256) {
        int d = idx >> 4, tk = idx & 15;
        ys[d][tk] = y[(b * 432 + d) * 4096 + lbase + tk];
    }
    __syncthreads();

    float acc[16];
#pragma unroll
    for (int k = 0; k < 16; k++) acc[k] = 0.f;
    for (int d2 = 0; d2 < 216; d2++) {
        float2 w2 = wft2[d2 * 256 + t];
        const float4* y0 = (const float4*)&ys[2 * d2][0];
        const float4* y1 = (const float4*)&ys[2 * d2 + 1][0];
#pragma unroll
        for (int q = 0; q < 4; q++) {
            float4 a = y0[q], c = y1[q];
            acc[4 * q + 0] += w2.x * a.x + w2.y * c.x;
            acc[4 * q + 1] += w2.x * a.y + w2.y * c.y;
            acc[4 * q + 2] += w2.x * a.z + w2.y * c.z;
            acc[4 * q + 3] += w2.x * a.w + w2.y * c.w;
        }
    }
#pragma unroll
    for (int q = 0; q < 4; q++)
        *(float4*)&vs[t][4 * q] = *(float4*)&acc[4 * q];
    __syncthreads();

    {
        int tk = t >> 4, sub = t & 15;
        float s = 0.f, s2 = 0.f;
        for (int m = 0; m < 16; m++) {
            float v = vs[sub * 16 + m][tk];
            s += v; s2 += v * v;
        }
        s  += __shfl_xor(s, 1, 64);  s2 += __shfl_xor(s2, 1, 64);
        s  += __shfl_xor(s, 2, 64);  s2 += __shfl_xor(s2, 2, 64);
        s  += __shfl_xor(s, 4, 64);  s2 += __shfl_xor(s2, 4, 64);
        s  += __shfl_xor(s, 8, 64);  s2 += __shfl_xor(s2, 8, 64);
        if (sub == 0) {
            float mu = s * (1.f / 256.f);
            float var = s2 * (1.f / 256.f) - mu * mu;
            mu_s[tk] = mu;
            rs_s[tk] = rsqrtf(var + 1e-5f);
        }
    }
    __syncthreads();

    float g = ln_g[t], be = ln_b[t];
#pragma unroll
    for (int k = 0; k < 16; k++) {
        float zv = zbuf[(tokbase + k) * 256 + t];
        float sz = zv / (1.f + __expf(-zv));  // SiLU(z)
        vs[t][k] = ((acc[k] - mu_s[k]) * rs_s[k] * g + be) * sz;
    }
    __syncthreads();

    float oacc[8];
#pragma unroll
    for (int k = 0; k < 8; k++) oacc[k] = 0.f;
    int o = t & 127, kh = (t >> 7) * 8;
    for (int i2 = 0; i2 < 128; i2++) {
        float2 w2 = wot2[i2 * 128 + o];
        float4 v0 = *(const float4*)&vs[2 * i2][kh];
        float4 v1 = *(const float4*)&vs[2 * i2][kh + 4];
        float4 u0 = *(const float4*)&vs[2 * i2 + 1][kh];
        float4 u1 = *(const float4*)&vs[2 * i2 + 1][kh + 4];
        oacc[0] += w2.x * v0.x + w2.y * u0.x;
        oacc[1] += w2.x * v0.y + w2.y * u0.y;
        oacc[2] += w2.x * v0.z + w2.y * u0.z;
        oacc[3] += w2.x * v0.w + w2.y * u0.w;
        oacc[4] += w2.x * v1.x + w2.y * u1.x;
        oacc[5] += w2.x * v1.y + w2.y * u1.y;
        oacc[6] += w2.x * v1.z + w2.y * u1.z;
        oacc[7] += w2.x * v1.w + w2.y * u1.w;
    }
#pragma unroll
    for (int k = 0; k < 8; k++)
        out[(tokbase + kh + k) * 128 + o] = oacc[k];
}

// ---------------------------------------------------------------- launch
extern "C" void kernel_launch(void* const* d_in, const int* in_sizes, int n_in,
                              void* d_out, int out_size, void* d_ws, size_t ws_size,
                              hipStream_t stream) {
    const float* x        = (const float*)d_in[0];
    const float* w_in     = (const float*)d_in[1];
    const float* conv_w   = (const float*)d_in[2];
    const float* conv_b   = (const float*)d_in[3];
    const float* x_proj_w = (const float*)d_in[4];
    const float* dt_w     = (const float*)d_in[5];
    const float* dt_b     = (const float*)d_in[6];
    const float* A_logs   = (const float*)d_in[7];
    const float* Ds       = (const float*)d_in[8];
    const float* w_fold   = (const float*)d_in[9];
    const float* ln_g     = (const float*)d_in[10];
    const float* ln_b     = (const float*)d_in[11];
    const float* w_out    = (const float*)d_in[12];
    float* out = (float*)d_out;

    float* ws     = (float*)d_ws;
    float* xpt    = ws;                    // B*256*L       = 2,097,152
    float* zbuf   = xpt    + 2097152;      // NTOK*256      = 2,097,152
    float* xc     = zbuf   + 2097152;      // B*16*L        =   131,072
    float* dts    = xc     + 131072;       // B*14*L        =   114,688
    float* bc2    = dts    + 114688;       // B*32*L bf16   (slot float-sized)
    float* ybuf   = bc2    + 262144;       // B*432*L       = 3,538,944
    float* wint   = ybuf   + 3538944;      // 128*256 float2 =   65,536
    float* wft    = wint   + 65536;        // 432*256       =   110,592
    float* wot    = wft    + 110592;       // 256*128       =    32,768

    k_wprep<<<dim3(688), dim3(256), 0, stream>>>(w_in, w_fold, w_out,
                                                 (float2*)wint, wft, wot);
    k_inproj<<<dim3(NTOK / 16), dim3(256), 0, stream>>>(x, (const float2*)wint, xpt, zbuf);
    k_conv<<<dim3(NTOK / 256, CCONV), dim3(256), 0, stream>>>(xpt, conv_w, conv_b, xc);
    k_xdbl<<<dim3(NTOK / 256, 23), dim3(256), 0, stream>>>(xc, x_proj_w, dts, (__hip_bfloat16*)bc2);
    k_scan<<<dim3(BATCH * DSEQ), dim3(256), 0, stream>>>(xc, dts, (const unsigned short*)bc2,
                                                         dt_w, dt_b, A_logs, Ds, ybuf);
    k_tail<<<dim3(NTOK / 16), dim3(256), 0, stream>>>(ybuf, zbuf, (const float2*)wft,
                                                      ln_g, ln_b, (const float2*)wot, out);
}

// Round 15
// 213.068 us; speedup vs baseline: 1.4328x; 1.4328x over previous
//
#include <hip/hip_runtime.h>
#include <hip/hip_bf16.h>

// Problem constants
#define DM     128
#define DSTATE 16
#define DINNER 256
#define CCONV  16
#define NEIGH  27
#define DSEQ   432   // CCONV * NEIGH
#define DTRANK 14
#define LVOL   4096  // 16*16*16
#define BATCH  2
#define NTOK   8192  // BATCH * LVOL

typedef __attribute__((ext_vector_type(8))) unsigned short ushort8_t;

__device__ __forceinline__ float bf2f(unsigned short u) {
    union { unsigned int i; float f; } v; v.i = ((unsigned int)u) << 16; return v.f;
}

// ---------------------------------------------------------------- merged weight prep
__global__ void k_wprep(const float* __restrict__ w_in, const float* __restrict__ w_fold,
                        const float* __restrict__ w_out, float2* __restrict__ wint2,
                        float* __restrict__ wft2, float* __restrict__ wot2) {
    int idx = blockIdx.x * 256 + threadIdx.x;
    if (idx < 32768) {
        int j = idx >> 8, t = idx & 255;
        wint2[idx] = make_float2(w_in[t * 128 + j], w_in[(t + 256) * 128 + j]);
    } else if (idx < 32768 + 110592) {
        int local = idx - 32768;
        int t = local / 432, d = local - t * 432;
        wft2[(d >> 1) * 512 + t * 2 + (d & 1)] = w_fold[t * 432 + d];
    } else if (idx < 32768 + 110592 + 32768) {
        int local = idx - 32768 - 110592;
        int o = local >> 8, i = local & 255;
        wot2[(i >> 1) * 256 + o * 2 + (i & 1)] = w_out[o * 256 + i];
    }
}

// ---------------------------------------------------------------- in-proj GEMM
__global__ void k_inproj(const float* __restrict__ x, const float2* __restrict__ wint2,
                         float* __restrict__ xpt, float* __restrict__ zbuf) {
    int t = threadIdx.x;
    int tokbase = blockIdx.x * 16;
    int b = tokbase >> 12, lb = tokbase & 4095;
    __shared__ float xs_[16][128];
    for (int idx = t; idx < 2048; idx += 256)
        xs_[idx >> 7][idx & 127] = x[tokbase * 128 + idx];
    __syncthreads();
    float a0[16], a1[16];
#pragma unroll
    for (int k = 0; k < 16; k++) { a0[k] = 0.f; a1[k] = 0.f; }
    for (int j = 0; j < 128; j += 4) {
        float2 w0 = wint2[(j + 0) * 256 + t];
        float2 w1 = wint2[(j + 1) * 256 + t];
        float2 w2 = wint2[(j + 2) * 256 + t];
        float2 w3 = wint2[(j + 3) * 256 + t];
#pragma unroll
        for (int k = 0; k < 16; k++) {
            float4 xv = *(const float4*)&xs_[k][j];
            a0[k] += xv.x * w0.x + xv.y * w1.x + xv.z * w2.x + xv.w * w3.x;
            a1[k] += xv.x * w0.y + xv.y * w1.y + xv.z * w2.y + xv.w * w3.y;
        }
    }
    float* xr = xpt + (size_t)(b * 256 + t) * 4096 + lb;
#pragma unroll
    for (int k = 0; k < 16; k++) xr[k] = a0[k];
#pragma unroll
    for (int k = 0; k < 16; k++) zbuf[(tokbase + k) * 256 + t] = a1[k];
}

// ---------------------------------------------------------------- grouped conv3d + SiLU
__global__ void k_conv(const float* __restrict__ xpt, const float* __restrict__ conv_w,
                       const float* __restrict__ conv_b, float* __restrict__ xc) {
    int t = threadIdx.x;
    int tok = blockIdx.x * 256 + t;
    int co = blockIdx.y;
    int b = tok >> 12, l = tok & 4095;
    int d0 = l >> 8, h0 = (l >> 4) & 15, w0 = l & 15;
    __shared__ float wl[432];
    for (int i = t; i < 432; i += 256) wl[i] = conv_w[co * 432 + i];  // [q][27]
    __syncthreads();
    int nbo[27];
#pragma unroll
    for (int t27 = 0; t27 < 27; t27++) {
        int di = t27 / 9 - 1, dj = (t27 / 3) % 3 - 1, dk = t27 % 3 - 1;
        int zd = d0 + di, zh = h0 + dj, zw = w0 + dk;
        nbo[t27] = ((unsigned)zd > 15u || (unsigned)zh > 15u || (unsigned)zw > 15u)
                   ? -1 : ((zd << 8) + (zh << 4) + zw);
    }
    const float* xb = xpt + (size_t)(b * 256 + co * 16) * 4096;
    float acc0 = conv_b[co], acc1 = 0.f;
    for (int t27 = 0; t27 < 27; t27++) {
        int o = nbo[t27];
        if (o >= 0) {
#pragma unroll
            for (int q = 0; q < 16; q += 2) {
                acc0 += xb[q * 4096 + o]       * wl[q * 27 + t27];
                acc1 += xb[(q + 1) * 4096 + o] * wl[(q + 1) * 27 + t27];
            }
        }
    }
    float acc = acc0 + acc1;
    acc = acc / (1.f + __expf(-acc));  // SiLU
    xc[(b * 16 + co) * 4096 + l] = acc;
}

// ---------------------------------------------------------------- x_dbl = x_proj_w @ unfold(xc)
// FOUR channels per block (y, y+12, y+24, y+36; guard <46): gather shared.
__global__ void k_xdbl(const float* __restrict__ xc, const float* __restrict__ x_proj_w,
                       float* __restrict__ dts, __hip_bfloat16* __restrict__ bc2) {
    int t = threadIdx.x;
    int tok = blockIdx.x * 256 + t;
    int cy = blockIdx.y;          // 0..11
    int b = tok >> 12, l = tok & 4095;
    int d0 = l >> 8, h0 = (l >> 4) & 15, w0 = l & 15;
    __shared__ float wl[4][432];
    for (int i = t; i < 432; i += 256) {
#pragma unroll
        for (int cc = 0; cc < 4; cc++) {
            int c = cy + cc * 12;
            wl[cc][i] = (c < 46) ? x_proj_w[c * 432 + i] : 0.f;
        }
    }
    __syncthreads();
    int nbo[27];
#pragma unroll
    for (int t27 = 0; t27 < 27; t27++) {
        int di = t27 / 9 - 1, dj = (t27 / 3) % 3 - 1, dk = t27 % 3 - 1;
        int zd = d0 + di, zh = h0 + dj, zw = w0 + dk;
        nbo[t27] = ((unsigned)zd > 15u || (unsigned)zh > 15u || (unsigned)zw > 15u)
                   ? -1 : ((zd << 8) + (zh << 4) + zw);
    }
    const float* xcb = xc + b * 16 * 4096;
    float acc[4];
#pragma unroll
    for (int cc = 0; cc < 4; cc++) acc[cc] = 0.f;
    for (int t27 = 0; t27 < 27; t27++) {
        int o = nbo[t27];
        if (o >= 0) {
#pragma unroll
            for (int ch = 0; ch < 16; ch += 2) {
                float v0 = xcb[ch * 4096 + o];
                float v1 = xcb[(ch + 1) * 4096 + o];
                int i0 = ch * 27 + t27, i1 = (ch + 1) * 27 + t27;
#pragma unroll
                for (int cc = 0; cc < 4; cc++)
                    acc[cc] += v0 * wl[cc][i0] + v1 * wl[cc][i1];
            }
        }
    }
#pragma unroll
    for (int cc = 0; cc < 4; cc++) {
        int c = cy + cc * 12;
        if (c < 14)
            dts[(size_t)(b * 14 + c) * 4096 + l] = acc[cc];
        else if (c < 46)
            bc2[(size_t)(b * 32 + (c - 14)) * 4096 + l] = __float2bfloat16(acc[cc]);
    }
}

// ---------------------------------------------------------------- selective scan (+ fused delta)
// R12's exact kernel (89.6 us, no spill): 512 thr, l in [t*8,t*8+8), l-major
// bf16 bc2, n-outer, 1-deep B/C prefetch, A[n]=-(n+1) fast path + fallback.
__global__ __launch_bounds__(512, 2) void k_scan(
        const float* __restrict__ xc, const float* __restrict__ dts,
        const unsigned short* __restrict__ bc2, const float* __restrict__ dt_w,
        const float* __restrict__ dt_b, const float* __restrict__ A_logs,
        const float* __restrict__ Ds, float* __restrict__ y) {
    int bd = blockIdx.x;
    int b = bd / 432, dch = bd % 432;
    int t = threadIdx.x;               // 0..511
    int lane = t & 63, wv = t >> 6;    // 8 waves

    float A[16];
    bool intA = true;
#pragma unroll
    for (int n = 0; n < 16; n++) {
        A[n] = -__expf(A_logs[dch * 16 + n]);
        intA = intA && (fabsf(A[n] + (float)(n + 1)) < 1e-3f);
    }
    float Dskip = Ds[dch];

    int cch = dch / 27, t27 = dch % 27;
    int di = t27 / 9 - 1, dj = (t27 / 3) % 3 - 1, dk = t27 % 3 - 1;

    // ---- fused delta: softplus(sum_r dts[b][r][l]*dt_w[dch][r] + dt_b[dch])
    float dtv[8];
    {
        float s[8];
        float bias = dt_b[dch];
#pragma unroll
        for (int i = 0; i < 8; i++) s[i] = bias;
        const float* dsb = dts + (size_t)(b * 14) * 4096 + t * 8;
#pragma unroll
        for (int r = 0; r < 14; r++) {
            float d8[8];
            *(float4*)&d8[0] = *(const float4*)(dsb + (size_t)r * 4096);
            *(float4*)&d8[4] = *(const float4*)(dsb + (size_t)r * 4096 + 4);
            float w = dt_w[dch * 14 + r];
#pragma unroll
            for (int i = 0; i < 8; i++) s[i] += d8[i] * w;
        }
#pragma unroll
        for (int i = 0; i < 8; i++)
            dtv[i] = (s[i] > 15.f) ? s[i] : log1pf(__expf(s[i]));
    }

    // ---- u gather; ys pre-init with Dskip*u
    int d0 = t >> 5, h0 = (t >> 1) & 15, w0 = (t & 1) << 3;
    int zd = d0 + di, zh = h0 + dj;
    bool rowok = ((unsigned)zd <= 15u) && ((unsigned)zh <= 15u);
    const float* xr = xc + (size_t)(b * 16 + cch) * 4096 + (zd << 8) + (zh << 4);
    float dtu[8], ys[8];
#pragma unroll
    for (int i = 0; i < 8; i++) {
        int zw = w0 + i + dk;
        float u = (rowok && (unsigned)zw <= 15u) ? xr[zw] : 0.f;
        dtu[i] = dtv[i] * u;
        ys[i] = Dskip * u;
    }

    const unsigned short* bcb = bc2 + (size_t)(b * 32) * 4096 + t * 8;

    // ---- pass 1: chunk transform (Ap, Bp) per state; B prefetched 1-deep
    float Ap[16], Bp[16];
    if (intA) {
        float av[8], aw[8];
#pragma unroll
        for (int i = 0; i < 8; i++) { av[i] = __expf(-dtv[i]); aw[i] = av[i]; }
        float P = ((av[0] * av[1]) * (av[2] * av[3])) * ((av[4] * av[5]) * (av[6] * av[7]));
        float ApAcc = P;
        ushort8_t Bnx = *(const ushort8_t*)(bcb);
#pragma unroll
        for (int n = 0; n < 16; n++) {
            ushort8_t Bv = Bnx;
            if (n < 15) Bnx = *(const ushort8_t*)(bcb + (size_t)(n + 1) * 4096);
            float bp = 0.f;
#pragma unroll
            for (int i = 0; i < 8; i++)
                bp = aw[i] * bp + dtu[i] * bf2f(Bv[i]);
            Ap[n] = ApAcc; Bp[n] = bp;
            if (n < 15) {
#pragma unroll
                for (int i = 0; i < 8; i++) aw[i] *= av[i];
                ApAcc *= P;
            }
        }
    } else {
        ushort8_t Bnx = *(const ushort8_t*)(bcb);
#pragma unroll
        for (int n = 0; n < 16; n++) {
            ushort8_t Bv = Bnx;
            if (n < 15) Bnx = *(const ushort8_t*)(bcb + (size_t)(n + 1) * 4096);
            float ap = 1.f, bp = 0.f, An = A[n];
#pragma unroll
            for (int i = 0; i < 8; i++) {
                float a = __expf(dtv[i] * An);
                bp = a * bp + dtu[i] * bf2f(Bv[i]);
                ap *= a;
            }
            Ap[n] = ap; Bp[n] = bp;
        }
    }

    // ---- wave-level inclusive scan (Hillis-Steele over 64 lanes)
#pragma unroll
    for (int s = 1; s < 64; s <<= 1) {
#pragma unroll
        for (int n = 0; n < 16; n++) {
            float pa = __shfl_up(Ap[n], s, 64);
            float pb = __shfl_up(Bp[n], s, 64);
            if (lane >= s) {
                Bp[n] = Ap[n] * pb + Bp[n];   // combine(earlier=(pa,pb), later)
                Ap[n] *= pa;
            }
        }
    }

    // ---- cross-wave prefix via tiny LDS
    __shared__ float waggA[8][16], waggB[8][16];
    if (lane == 63) {
#pragma unroll
        for (int n = 0; n < 16; n++) { waggA[wv][n] = Ap[n]; waggB[wv][n] = Bp[n]; }
    }
    __syncthreads();

    float h[16];
#pragma unroll
    for (int n = 0; n < 16; n++) {
        float exA = __shfl_up(Ap[n], 1, 64);
        float exB = __shfl_up(Bp[n], 1, 64);
        if (lane == 0) { exA = 1.f; exB = 0.f; }
        float WB = 0.f;
        for (int ww = 0; ww < wv; ww++)
            WB = waggA[ww][n] * WB + waggB[ww][n];
        h[n] = exA * WB + exB;     // incoming state for this chunk
    }

    // ---- pass 2: rescan with incoming state; B,C prefetched 1-deep
    if (intA) {
        float av[8], aw[8];
#pragma unroll
        for (int i = 0; i < 8; i++) { av[i] = __expf(-dtv[i]); aw[i] = av[i]; }
        ushort8_t Bnx = *(const ushort8_t*)(bcb);
        ushort8_t Cnx = *(const ushort8_t*)(bcb + (size_t)16 * 4096);
#pragma unroll
        for (int n = 0; n < 16; n++) {
            ushort8_t Bv = Bnx, Cv = Cnx;
            if (n < 15) {
                Bnx = *(const ushort8_t*)(bcb + (size_t)(n + 1) * 4096);
                Cnx = *(const ushort8_t*)(bcb + (size_t)(17 + n) * 4096);
            }
            float hn = h[n];
#pragma unroll
            for (int i = 0; i < 8; i++) {
                hn = aw[i] * hn + dtu[i] * bf2f(Bv[i]);
                ys[i] += hn * bf2f(Cv[i]);
            }
            if (n < 15) {
#pragma unroll
                for (int i = 0; i < 8; i++) aw[i] *= av[i];
            }
        }
    } else {
        ushort8_t Bnx = *(const ushort8_t*)(bcb);
        ushort8_t Cnx = *(const ushort8_t*)(bcb + (size_t)16 * 4096);
#pragma unroll
        for (int n = 0; n < 16; n++) {
            ushort8_t Bv = Bnx, Cv = Cnx;
            if (n < 15) {
                Bnx = *(const ushort8_t*)(bcb + (size_t)(n + 1) * 4096);
                Cnx = *(const ushort8_t*)(bcb + (size_t)(17 + n) * 4096);
            }
            float hn = h[n], An = A[n];
#pragma unroll
            for (int i = 0; i < 8; i++) {
                float a = __expf(dtv[i] * An);
                hn = a * hn + dtu[i] * bf2f(Bv[i]);
                ys[i] += hn * bf2f(Cv[i]);
            }
        }
    }

    float* yo = y + (size_t)(b * 432 + dch) * 4096 + t * 8;
    *(float4*)(yo)     = *(float4*)&ys[0];
    *(float4*)(yo + 4) = *(float4*)&ys[4];
}

// ---------------------------------------------------------------- fold GEMM + LN + gate + out GEMM
__global__ void k_tail(const float* __restrict__ y, const float* __restrict__ zbuf,
                       const float2* __restrict__ wft2, const float* __restrict__ ln_g,
                       const float* __restrict__ ln_b, const float2* __restrict__ wot2,
                       float* __restrict__ out) {
    int t = threadIdx.x;
    int tokbase = blockIdx.x * 16;
    int b = tokbase >> 12, lbase = tokbase & 4095;
    __shared__ float ys[432][16];
    __shared__ float vs[256][20];
    __shared__ float mu_s[16], rs_s[16];

    for (int idx = t; idx < 432 * 16; idx += 256) {
        int d = idx >> 4, tk = idx & 15;
        ys[d][tk] = y[(b * 432 + d) * 4096 + lbase + tk];
    }
    __syncthreads();

    float acc[16];
#pragma unroll
    for (int k = 0; k < 16; k++) acc[k] = 0.f;
    for (int d2 = 0; d2 < 216; d2++) {
        float2 w2 = wft2[d2 * 256 + t];
        const float4* y0 = (const float4*)&ys[2 * d2][0];
        const float4* y1 = (const float4*)&ys[2 * d2 + 1][0];
#pragma unroll
        for (int q = 0; q < 4; q++) {
            float4 a = y0[q], c = y1[q];
            acc[4 * q + 0] += w2.x * a.x + w2.y * c.x;
            acc[4 * q + 1] += w2.x * a.y + w2.y * c.y;
            acc[4 * q + 2] += w2.x * a.z + w2.y * c.z;
            acc[4 * q + 3] += w2.x * a.w + w2.y * c.w;
        }
    }
#pragma unroll
    for (int q = 0; q < 4; q++)
        *(float4*)&vs[t][4 * q] = *(float4*)&acc[4 * q];
    __syncthreads();

    {
        int tk = t >> 4, sub = t & 15;
        float s = 0.f, s2 = 0.f;
        for (int m = 0; m < 16; m++) {
            float v = vs[sub * 16 + m][tk];
            s += v; s2 += v * v;
        }
        s  += __shfl_xor(s, 1, 64);  s2 += __shfl_xor(s2, 1, 64);
        s  += __shfl_xor(s, 2, 64);  s2 += __shfl_xor(s2, 2, 64);
        s  += __shfl_xor(s, 4, 64);  s2 += __shfl_xor(s2, 4, 64);
        s  += __shfl_xor(s, 8, 64);  s2 += __shfl_xor(s2, 8, 64);
        if (sub == 0) {
            float mu = s * (1.f / 256.f);
            float var = s2 * (1.f / 256.f) - mu * mu;
            mu_s[tk] = mu;
            rs_s[tk] = rsqrtf(var + 1e-5f);
        }
    }
    __syncthreads();

    float g = ln_g[t], be = ln_b[t];
#pragma unroll
    for (int k = 0; k < 16; k++) {
        float zv = zbuf[(tokbase + k) * 256 + t];
        float sz = zv / (1.f + __expf(-zv));  // SiLU(z)
        vs[t][k] = ((acc[k] - mu_s[k]) * rs_s[k] * g + be) * sz;
    }
    __syncthreads();

    float oacc[8];
#pragma unroll
    for (int k = 0; k < 8; k++) oacc[k] = 0.f;
    int o = t & 127, kh = (t >> 7) * 8;
    for (int i2 = 0; i2 < 128; i2++) {
        float2 w2 = wot2[i2 * 128 + o];
        float4 v0 = *(const float4*)&vs[2 * i2][kh];
        float4 v1 = *(const float4*)&vs[2 * i2][kh + 4];
        float4 u0 = *(const float4*)&vs[2 * i2 + 1][kh];
        float4 u1 = *(const float4*)&vs[2 * i2 + 1][kh + 4];
        oacc[0] += w2.x * v0.x + w2.y * u0.x;
        oacc[1] += w2.x * v0.y + w2.y * u0.y;
        oacc[2] += w2.x * v0.z + w2.y * u0.z;
        oacc[3] += w2.x * v0.w + w2.y * u0.w;
        oacc[4] += w2.x * v1.x + w2.y * u1.x;
        oacc[5] += w2.x * v1.y + w2.y * u1.y;
        oacc[6] += w2.x * v1.z + w2.y * u1.z;
        oacc[7] += w2.x * v1.w + w2.y * u1.w;
    }
#pragma unroll
    for (int k = 0; k < 8; k++)
        out[(tokbase + kh + k) * 128 + o] = oacc[k];
}

// ---------------------------------------------------------------- launch
extern "C" void kernel_launch(void* const* d_in, const int* in_sizes, int n_in,
                              void* d_out, int out_size, void* d_ws, size_t ws_size,
                              hipStream_t stream) {
    const float* x        = (const float*)d_in[0];
    const float* w_in     = (const float*)d_in[1];
    const float* conv_w   = (const float*)d_in[2];
    const float* conv_b   = (const float*)d_in[3];
    const float* x_proj_w = (const float*)d_in[4];
    const float* dt_w     = (const float*)d_in[5];
    const float* dt_b     = (const float*)d_in[6];
    const float* A_logs   = (const float*)d_in[7];
    const float* Ds       = (const float*)d_in[8];
    const float* w_fold   = (const float*)d_in[9];
    const float* ln_g     = (const float*)d_in[10];
    const float* ln_b     = (const float*)d_in[11];
    const float* w_out    = (const float*)d_in[12];
    float* out = (float*)d_out;

    float* ws     = (float*)d_ws;
    float* xpt    = ws;                    // B*256*L       = 2,097,152
    float* zbuf   = xpt    + 2097152;      // NTOK*256      = 2,097,152
    float* xc     = zbuf   + 2097152;      // B*16*L        =   131,072
    float* dts    = xc     + 131072;       // B*14*L        =   114,688
    float* bc2    = dts    + 114688;       // B*32*L bf16   (slot float-sized)
    float* ybuf   = bc2    + 262144;       // B*432*L       = 3,538,944
    float* wint   = ybuf   + 3538944;      // 128*256 float2 =   65,536
    float* wft    = wint   + 65536;        // 432*256       =   110,592
    float* wot    = wft    + 110592;       // 256*128       =    32,768

    k_wprep<<<dim3(688), dim3(256), 0, stream>>>(w_in, w_fold, w_out,
                                                 (float2*)wint, wft, wot);
    k_inproj<<<dim3(NTOK / 16), dim3(256), 0, stream>>>(x, (const float2*)wint, xpt, zbuf);
    k_conv<<<dim3(NTOK / 256, CCONV), dim3(256), 0, stream>>>(xpt, conv_w, conv_b, xc);
    k_xdbl<<<dim3(NTOK / 256, 12), dim3(256), 0, stream>>>(xc, x_proj_w, dts, (__hip_bfloat16*)bc2);
    k_scan<<<dim3(BATCH * DSEQ), dim3(512), 0, stream>>>(xc, dts, (const unsigned short*)bc2,
                                                         dt_w, dt_b, A_logs, Ds, ybuf);
    k_tail<<<dim3(NTOK / 16), dim3(256), 0, stream>>>(ybuf, zbuf, (const float2*)wft,
                                                      ln_g, ln_b, (const float2*)wot, out);
}

// Round 16
// 185.725 us; speedup vs baseline: 1.6438x; 1.1472x over previous
//
#include <hip/hip_runtime.h>
#include <hip/hip_bf16.h>

// Problem constants
#define DM     128
#define DSTATE 16
#define DINNER 256
#define CCONV  16
#define NEIGH  27
#define DSEQ   432   // CCONV * NEIGH
#define DTRANK 14
#define LVOL   4096  // 16*16*16
#define BATCH  2
#define NTOK   8192  // BATCH * LVOL

typedef __attribute__((ext_vector_type(8))) unsigned short ushort8_t;

__device__ __forceinline__ float bf2f(unsigned short u) {
    union { unsigned int i; float f; } v; v.i = ((unsigned int)u) << 16; return v.f;
}

// ---------------------------------------------------------------- merged weight prep
__global__ void k_wprep(const float* __restrict__ w_in, const float* __restrict__ w_fold,
                        const float* __restrict__ w_out, float2* __restrict__ wint2,
                        float* __restrict__ wft2, float* __restrict__ wot2) {
    int idx = blockIdx.x * 256 + threadIdx.x;
    if (idx < 32768) {
        int j = idx >> 8, t = idx & 255;
        wint2[idx] = make_float2(w_in[t * 128 + j], w_in[(t + 256) * 128 + j]);
    } else if (idx < 32768 + 110592) {
        int local = idx - 32768;
        int t = local / 432, d = local - t * 432;
        wft2[(d >> 1) * 512 + t * 2 + (d & 1)] = w_fold[t * 432 + d];
    } else if (idx < 32768 + 110592 + 32768) {
        int local = idx - 32768 - 110592;
        int o = local >> 8, i = local & 255;
        wot2[(i >> 1) * 256 + o * 2 + (i & 1)] = w_out[o * 256 + i];
    }
}

// ---------------------------------------------------------------- in-proj GEMM
__global__ void k_inproj(const float* __restrict__ x, const float2* __restrict__ wint2,
                         float* __restrict__ xpt, float* __restrict__ zbuf) {
    int t = threadIdx.x;
    int tokbase = blockIdx.x * 16;
    int b = tokbase >> 12, lb = tokbase & 4095;
    __shared__ float xs_[16][128];
    for (int idx = t; idx < 2048; idx += 256)
        xs_[idx >> 7][idx & 127] = x[tokbase * 128 + idx];
    __syncthreads();
    float a0[16], a1[16];
#pragma unroll
    for (int k = 0; k < 16; k++) { a0[k] = 0.f; a1[k] = 0.f; }
    for (int j = 0; j < 128; j += 4) {
        float2 w0 = wint2[(j + 0) * 256 + t];
        float2 w1 = wint2[(j + 1) * 256 + t];
        float2 w2 = wint2[(j + 2) * 256 + t];
        float2 w3 = wint2[(j + 3) * 256 + t];
#pragma unroll
        for (int k = 0; k < 16; k++) {
            float4 xv = *(const float4*)&xs_[k][j];
            a0[k] += xv.x * w0.x + xv.y * w1.x + xv.z * w2.x + xv.w * w3.x;
            a1[k] += xv.x * w0.y + xv.y * w1.y + xv.z * w2.y + xv.w * w3.y;
        }
    }
    float* xr = xpt + (size_t)(b * 256 + t) * 4096 + lb;
#pragma unroll
    for (int k = 0; k < 16; k++) xr[k] = a0[k];
#pragma unroll
    for (int k = 0; k < 16; k++) zbuf[(tokbase + k) * 256 + t] = a1[k];
}

// ---------------------------------------------------------------- grouped conv3d + SiLU
__global__ void k_conv(const float* __restrict__ xpt, const float* __restrict__ conv_w,
                       const float* __restrict__ conv_b, float* __restrict__ xc) {
    int t = threadIdx.x;
    int tok = blockIdx.x * 256 + t;
    int co = blockIdx.y;
    int b = tok >> 12, l = tok & 4095;
    int d0 = l >> 8, h0 = (l >> 4) & 15, w0 = l & 15;
    __shared__ float wl[432];
    for (int i = t; i < 432; i += 256) wl[i] = conv_w[co * 432 + i];  // [q][27]
    __syncthreads();
    int nbo[27];
#pragma unroll
    for (int t27 = 0; t27 < 27; t27++) {
        int di = t27 / 9 - 1, dj = (t27 / 3) % 3 - 1, dk = t27 % 3 - 1;
        int zd = d0 + di, zh = h0 + dj, zw = w0 + dk;
        nbo[t27] = ((unsigned)zd > 15u || (unsigned)zh > 15u || (unsigned)zw > 15u)
                   ? -1 : ((zd << 8) + (zh << 4) + zw);
    }
    const float* xb = xpt + (size_t)(b * 256 + co * 16) * 4096;
    float acc0 = conv_b[co], acc1 = 0.f;
    for (int t27 = 0; t27 < 27; t27++) {
        int o = nbo[t27];
        if (o >= 0) {
#pragma unroll
            for (int q = 0; q < 16; q += 2) {
                acc0 += xb[q * 4096 + o]       * wl[q * 27 + t27];
                acc1 += xb[(q + 1) * 4096 + o] * wl[(q + 1) * 27 + t27];
            }
        }
    }
    float acc = acc0 + acc1;
    acc = acc / (1.f + __expf(-acc));  // SiLU
    xc[(b * 16 + co) * 4096 + l] = acc;
}

// ---------------------------------------------------------------- x_dbl = x_proj_w @ unfold(xc)
// TWO channels per block (c, c+23): gather shared, two LDS weight rows.
__global__ void k_xdbl(const float* __restrict__ xc, const float* __restrict__ x_proj_w,
                       float* __restrict__ dts, __hip_bfloat16* __restrict__ bc2) {
    int t = threadIdx.x;
    int tok = blockIdx.x * 256 + t;
    int c0 = blockIdx.y;          // 0..22
    int c1 = c0 + 23;             // 23..45
    int b = tok >> 12, l = tok & 4095;
    int d0 = l >> 8, h0 = (l >> 4) & 15, w0 = l & 15;
    __shared__ float wl0[432], wl1[432];
    for (int i = t; i < 432; i += 256) {
        wl0[i] = x_proj_w[c0 * 432 + i];
        wl1[i] = x_proj_w[c1 * 432 + i];
    }
    __syncthreads();
    int nbo[27];
#pragma unroll
    for (int t27 = 0; t27 < 27; t27++) {
        int di = t27 / 9 - 1, dj = (t27 / 3) % 3 - 1, dk = t27 % 3 - 1;
        int zd = d0 + di, zh = h0 + dj, zw = w0 + dk;
        nbo[t27] = ((unsigned)zd > 15u || (unsigned)zh > 15u || (unsigned)zw > 15u)
                   ? -1 : ((zd << 8) + (zh << 4) + zw);
    }
    const float* xcb = xc + b * 16 * 4096;
    float a00 = 0.f, a01 = 0.f, a10 = 0.f, a11 = 0.f;
    for (int t27 = 0; t27 < 27; t27++) {
        int o = nbo[t27];
        if (o >= 0) {
#pragma unroll
            for (int ch = 0; ch < 16; ch += 2) {
                float v0 = xcb[ch * 4096 + o];
                float v1 = xcb[(ch + 1) * 4096 + o];
                int i0 = ch * 27 + t27, i1 = (ch + 1) * 27 + t27;
                a00 += v0 * wl0[i0];
                a01 += v1 * wl0[i1];
                a10 += v0 * wl1[i0];
                a11 += v1 * wl1[i1];
            }
        }
    }
    float acc0 = a00 + a01;
    float acc1 = a10 + a11;
    if (c0 < 14)
        dts[(size_t)(b * 14 + c0) * 4096 + l] = acc0;
    else
        bc2[(size_t)(b * 32 + (c0 - 14)) * 4096 + l] = __float2bfloat16(acc0);
    bc2[(size_t)(b * 32 + (c1 - 14)) * 4096 + l] = __float2bfloat16(acc1);
}

// ---------------------------------------------------------------- selective scan (+ fused delta)
// 512 thr/block, l in [t*8,t*8+8), l-major bf16 bc2, n-outer, 1-deep prefetch.
// FAST PATH (A[n] = -(n+1)): scan monoid represented as (sdt, Bp[16]) —
// sdt combines by ADDITION; Ap[n] recovered as exp(-sdt)^(n+1).
// 17 shuffled values/step instead of 32 (~47% fewer ds_bpermute).
// Fallback path = R12 verbatim (exact exp per state).
__global__ __launch_bounds__(512, 2) void k_scan(
        const float* __restrict__ xc, const float* __restrict__ dts,
        const unsigned short* __restrict__ bc2, const float* __restrict__ dt_w,
        const float* __restrict__ dt_b, const float* __restrict__ A_logs,
        const float* __restrict__ Ds, float* __restrict__ y) {
    int bd = blockIdx.x;
    int b = bd / 432, dch = bd % 432;
    int t = threadIdx.x;               // 0..511
    int lane = t & 63, wv = t >> 6;    // 8 waves

    bool intA = true;
#pragma unroll
    for (int n = 0; n < 16; n++) {
        float An = -__expf(A_logs[dch * 16 + n]);
        intA = intA && (fabsf(An + (float)(n + 1)) < 1e-3f);
    }
    float Dskip = Ds[dch];

    int cch = dch / 27, t27 = dch % 27;
    int di = t27 / 9 - 1, dj = (t27 / 3) % 3 - 1, dk = t27 % 3 - 1;

    // ---- fused delta: softplus(sum_r dts[b][r][l]*dt_w[dch][r] + dt_b[dch])
    float dtv[8];
    {
        float s[8];
        float bias = dt_b[dch];
#pragma unroll
        for (int i = 0; i < 8; i++) s[i] = bias;
        const float* dsb = dts + (size_t)(b * 14) * 4096 + t * 8;
#pragma unroll
        for (int r = 0; r < 14; r++) {
            float d8[8];
            *(float4*)&d8[0] = *(const float4*)(dsb + (size_t)r * 4096);
            *(float4*)&d8[4] = *(const float4*)(dsb + (size_t)r * 4096 + 4);
            float w = dt_w[dch * 14 + r];
#pragma unroll
            for (int i = 0; i < 8; i++) s[i] += d8[i] * w;
        }
#pragma unroll
        for (int i = 0; i < 8; i++)
            dtv[i] = (s[i] > 15.f) ? s[i] : log1pf(__expf(s[i]));
    }

    // ---- u gather; ys pre-init with Dskip*u
    int d0 = t >> 5, h0 = (t >> 1) & 15, w0 = (t & 1) << 3;
    int zd = d0 + di, zh = h0 + dj;
    bool rowok = ((unsigned)zd <= 15u) && ((unsigned)zh <= 15u);
    const float* xr = xc + (size_t)(b * 16 + cch) * 4096 + (zd << 8) + (zh << 4);
    float dtu[8], ys[8];
#pragma unroll
    for (int i = 0; i < 8; i++) {
        int zw = w0 + i + dk;
        float u = (rowok && (unsigned)zw <= 15u) ? xr[zw] : 0.f;
        dtu[i] = dtv[i] * u;
        ys[i] = Dskip * u;
    }

    const unsigned short* bcb = bc2 + (size_t)(b * 32) * 4096 + t * 8;

    __shared__ float waggA[8][16], waggB[8][16];
    __shared__ float waggS[8];

    float h[16];
    float av[8];

    if (intA) {
        // ======================= FAST PATH =======================
        float aw[8];
#pragma unroll
        for (int i = 0; i < 8; i++) { av[i] = __expf(-dtv[i]); aw[i] = av[i]; }
        float sdt = ((dtv[0] + dtv[1]) + (dtv[2] + dtv[3]))
                  + ((dtv[4] + dtv[5]) + (dtv[6] + dtv[7]));

        // pass 1: Bp only (no Ap array); B prefetched 1-deep
        float Bp[16];
        {
            ushort8_t Bnx = *(const ushort8_t*)(bcb);
#pragma unroll
            for (int n = 0; n < 16; n++) {
                ushort8_t Bv = Bnx;
                if (n < 15) Bnx = *(const ushort8_t*)(bcb + (size_t)(n + 1) * 4096);
                float bp = 0.f;
#pragma unroll
                for (int i = 0; i < 8; i++)
                    bp = aw[i] * bp + dtu[i] * bf2f(Bv[i]);
                Bp[n] = bp;
                if (n < 15) {
#pragma unroll
                    for (int i = 0; i < 8; i++) aw[i] *= av[i];
                }
            }
        }

        // wave-level inclusive scan over (sdt, Bp[16])
#pragma unroll
        for (int s = 1; s < 64; s <<= 1) {
            float psdt = __shfl_up(sdt, s, 64);
            float pl = __expf(-sdt);   // later-segment decay base (before update)
            float pb[16];
#pragma unroll
            for (int n = 0; n < 16; n++) pb[n] = __shfl_up(Bp[n], s, 64);
            if (lane >= s) {
                float pw = pl;
#pragma unroll
                for (int n = 0; n < 16; n++) {
                    Bp[n] = pw * pb[n] + Bp[n];
                    pw *= pl;
                }
                sdt += psdt;
            }
        }

        // cross-wave prefix via tiny LDS
        if (lane == 63) {
            waggS[wv] = sdt;
#pragma unroll
            for (int n = 0; n < 16; n++) waggB[wv][n] = Bp[n];
        }
        __syncthreads();

        float exsdt = __shfl_up(sdt, 1, 64);
        float exB[16];
#pragma unroll
        for (int n = 0; n < 16; n++) exB[n] = __shfl_up(Bp[n], 1, 64);
        if (lane == 0) {
            exsdt = 0.f;
#pragma unroll
            for (int n = 0; n < 16; n++) exB[n] = 0.f;
        }
        float WB[16];
#pragma unroll
        for (int n = 0; n < 16; n++) WB[n] = 0.f;
        for (int ww = 0; ww < wv; ww++) {
            float plw = __expf(-waggS[ww]);
            float pww = plw;
#pragma unroll
            for (int n = 0; n < 16; n++) {
                WB[n] = pww * WB[n] + waggB[ww][n];
                pww *= plw;
            }
        }
        float pex = __expf(-exsdt);
        float pwx = pex;
#pragma unroll
        for (int n = 0; n < 16; n++) {
            h[n] = pwx * WB[n] + exB[n];
            pwx *= pex;
        }
    } else {
        // ======================= FALLBACK (R12 verbatim) =======================
        float A[16];
#pragma unroll
        for (int n = 0; n < 16; n++) A[n] = -__expf(A_logs[dch * 16 + n]);
        float Ap[16], Bp[16];
        ushort8_t Bnx = *(const ushort8_t*)(bcb);
#pragma unroll
        for (int n = 0; n < 16; n++) {
            ushort8_t Bv = Bnx;
            if (n < 15) Bnx = *(const ushort8_t*)(bcb + (size_t)(n + 1) * 4096);
            float ap = 1.f, bp = 0.f, An = A[n];
#pragma unroll
            for (int i = 0; i < 8; i++) {
                float a = __expf(dtv[i] * An);
                bp = a * bp + dtu[i] * bf2f(Bv[i]);
                ap *= a;
            }
            Ap[n] = ap; Bp[n] = bp;
        }
#pragma unroll
        for (int s = 1; s < 64; s <<= 1) {
#pragma unroll
            for (int n = 0; n < 16; n++) {
                float pa = __shfl_up(Ap[n], s, 64);
                float pb = __shfl_up(Bp[n], s, 64);
                if (lane >= s) {
                    Bp[n] = Ap[n] * pb + Bp[n];
                    Ap[n] *= pa;
                }
            }
        }
        if (lane == 63) {
#pragma unroll
            for (int n = 0; n < 16; n++) { waggA[wv][n] = Ap[n]; waggB[wv][n] = Bp[n]; }
        }
        __syncthreads();
#pragma unroll
        for (int n = 0; n < 16; n++) {
            float exA = __shfl_up(Ap[n], 1, 64);
            float exB = __shfl_up(Bp[n], 1, 64);
            if (lane == 0) { exA = 1.f; exB = 0.f; }
            float WB = 0.f;
            for (int ww = 0; ww < wv; ww++)
                WB = waggA[ww][n] * WB + waggB[ww][n];
            h[n] = exA * WB + exB;
        }
    }

    // ---- pass 2: rescan with incoming state; B,C prefetched 1-deep
    if (intA) {
        float aw[8];
#pragma unroll
        for (int i = 0; i < 8; i++) aw[i] = av[i];
        ushort8_t Bnx = *(const ushort8_t*)(bcb);
        ushort8_t Cnx = *(const ushort8_t*)(bcb + (size_t)16 * 4096);
#pragma unroll
        for (int n = 0; n < 16; n++) {
            ushort8_t Bv = Bnx, Cv = Cnx;
            if (n < 15) {
                Bnx = *(const ushort8_t*)(bcb + (size_t)(n + 1) * 4096);
                Cnx = *(const ushort8_t*)(bcb + (size_t)(17 + n) * 4096);
            }
            float hn = h[n];
#pragma unroll
            for (int i = 0; i < 8; i++) {
                hn = aw[i] * hn + dtu[i] * bf2f(Bv[i]);
                ys[i] += hn * bf2f(Cv[i]);
            }
            if (n < 15) {
#pragma unroll
                for (int i = 0; i < 8; i++) aw[i] *= av[i];
            }
        }
    } else {
        ushort8_t Bnx = *(const ushort8_t*)(bcb);
        ushort8_t Cnx = *(const ushort8_t*)(bcb + (size_t)16 * 4096);
#pragma unroll
        for (int n = 0; n < 16; n++) {
            float An = -__expf(A_logs[dch * 16 + n]);
            ushort8_t Bv = Bnx, Cv = Cnx;
            if (n < 15) {
                Bnx = *(const ushort8_t*)(bcb + (size_t)(n + 1) * 4096);
                Cnx = *(const ushort8_t*)(bcb + (size_t)(17 + n) * 4096);
            }
            float hn = h[n];
#pragma unroll
            for (int i = 0; i < 8; i++) {
                float a = __expf(dtv[i] * An);
                hn = a * hn + dtu[i] * bf2f(Bv[i]);
                ys[i] += hn * bf2f(Cv[i]);
            }
        }
    }

    float* yo = y + (size_t)(b * 432 + dch) * 4096 + t * 8;
    *(float4*)(yo)     = *(float4*)&ys[0];
    *(float4*)(yo + 4) = *(float4*)&ys[4];
}

// ---------------------------------------------------------------- fold GEMM + LN + gate + out GEMM
__global__ void k_tail(const float* __restrict__ y, const float* __restrict__ zbuf,
                       const float2* __restrict__ wft2, const float* __restrict__ ln_g,
                       const float* __restrict__ ln_b, const float2* __restrict__ wot2,
                       float* __restrict__ out) {
    int t = threadIdx.x;
    int tokbase = blockIdx.x * 16;
    int b = tokbase >> 12, lbase = tokbase & 4095;
    __shared__ float ys[432][16];
    __shared__ float vs[256][20];
    __shared__ float mu_s[16], rs_s[16];

    for (int idx = t; idx < 432 * 16; idx += 256) {
        int d = idx >> 4, tk = idx & 15;
        ys[d][tk] = y[(b * 432 + d) * 4096 + lbase + tk];
    }
    __syncthreads();

    float acc[16];
#pragma unroll
    for (int k = 0; k < 16; k++) acc[k] = 0.f;
    for (int d2 = 0; d2 < 216; d2++) {
        float2 w2 = wft2[d2 * 256 + t];
        const float4* y0 = (const float4*)&ys[2 * d2][0];
        const float4* y1 = (const float4*)&ys[2 * d2 + 1][0];
#pragma unroll
        for (int q = 0; q < 4; q++) {
            float4 a = y0[q], c = y1[q];
            acc[4 * q + 0] += w2.x * a.x + w2.y * c.x;
            acc[4 * q + 1] += w2.x * a.y + w2.y * c.y;
            acc[4 * q + 2] += w2.x * a.z + w2.y * c.z;
            acc[4 * q + 3] += w2.x * a.w + w2.y * c.w;
        }
    }
#pragma unroll
    for (int q = 0; q < 4; q++)
        *(float4*)&vs[t][4 * q] = *(float4*)&acc[4 * q];
    __syncthreads();

    {
        int tk = t >> 4, sub = t & 15;
        float s = 0.f, s2 = 0.f;
        for (int m = 0; m < 16; m++) {
            float v = vs[sub * 16 + m][tk];
            s += v; s2 += v * v;
        }
        s  += __shfl_xor(s, 1, 64);  s2 += __shfl_xor(s2, 1, 64);
        s  += __shfl_xor(s, 2, 64);  s2 += __shfl_xor(s2, 2, 64);
        s  += __shfl_xor(s, 4, 64);  s2 += __shfl_xor(s2, 4, 64);
        s  += __shfl_xor(s, 8, 64);  s2 += __shfl_xor(s2, 8, 64);
        if (sub == 0) {
            float mu = s * (1.f / 256.f);
            float var = s2 * (1.f / 256.f) - mu * mu;
            mu_s[tk] = mu;
            rs_s[tk] = rsqrtf(var + 1e-5f);
        }
    }
    __syncthreads();

    float g = ln_g[t], be = ln_b[t];
#pragma unroll
    for (int k = 0; k < 16; k++) {
        float zv = zbuf[(tokbase + k) * 256 + t];
        float sz = zv / (1.f + __expf(-zv));  // SiLU(z)
        vs[t][k] = ((acc[k] - mu_s[k]) * rs_s[k] * g + be) * sz;
    }
    __syncthreads();

    float oacc[8];
#pragma unroll
    for (int k = 0; k < 8; k++) oacc[k] = 0.f;
    int o = t & 127, kh = (t >> 7) * 8;
    for (int i2 = 0; i2 < 128; i2++) {
        float2 w2 = wot2[i2 * 128 + o];
        float4 v0 = *(const float4*)&vs[2 * i2][kh];
        float4 v1 = *(const float4*)&vs[2 * i2][kh + 4];
        float4 u0 = *(const float4*)&vs[2 * i2 + 1][kh];
        float4 u1 = *(const float4*)&vs[2 * i2 + 1][kh + 4];
        oacc[0] += w2.x * v0.x + w2.y * u0.x;
        oacc[1] += w2.x * v0.y + w2.y * u0.y;
        oacc[2] += w2.x * v0.z + w2.y * u0.z;
        oacc[3] += w2.x * v0.w + w2.y * u0.w;
        oacc[4] += w2.x * v1.x + w2.y * u1.x;
        oacc[5] += w2.x * v1.y + w2.y * u1.y;
        oacc[6] += w2.x * v1.z + w2.y * u1.z;
        oacc[7] += w2.x * v1.w + w2.y * u1.w;
    }
#pragma unroll
    for (int k = 0; k < 8; k++)
        out[(tokbase + kh + k) * 128 + o] = oacc[k];
}

// ---------------------------------------------------------------- launch
extern "C" void kernel_launch(void* const* d_in, const int* in_sizes, int n_in,
                              void* d_out, int out_size, void* d_ws, size_t ws_size,
                              hipStream_t stream) {
    const float* x        = (const float*)d_in[0];
    const float* w_in     = (const float*)d_in[1];
    const float* conv_w   = (const float*)d_in[2];
    const float* conv_b   = (const float*)d_in[3];
    const float* x_proj_w = (const float*)d_in[4];
    const float* dt_w     = (const float*)d_in[5];
    const float* dt_b     = (const float*)d_in[6];
    const float* A_logs   = (const float*)d_in[7];
    const float* Ds       = (const float*)d_in[8];
    const float* w_fold   = (const float*)d_in[9];
    const float* ln_g     = (const float*)d_in[10];
    const float* ln_b     = (const float*)d_in[11];
    const float* w_out    = (const float*)d_in[12];
    float* out = (float*)d_out;

    float* ws     = (float*)d_ws;
    float* xpt    = ws;                    // B*256*L       = 2,097,152
    float* zbuf   = xpt    + 2097152;      // NTOK*256      = 2,097,152
    float* xc     = zbuf   + 2097152;      // B*16*L        =   131,072
    float* dts    = xc     + 131072;       // B*14*L        =   114,688
    float* bc2    = dts    + 114688;       // B*32*L bf16   (slot float-sized)
    float* ybuf   = bc2    + 262144;       // B*432*L       = 3,538,944
    float* wint   = ybuf   + 3538944;      // 128*256 float2 =   65,536
    float* wft    = wint   + 65536;        // 432*256       =   110,592
    float* wot    = wft    + 110592;       // 256*128       =    32,768

    k_wprep<<<dim3(688), dim3(256), 0, stream>>>(w_in, w_fold, w_out,
                                                 (float2*)wint, wft, wot);
    k_inproj<<<dim3(NTOK / 16), dim3(256), 0, stream>>>(x, (const float2*)wint, xpt, zbuf);
    k_conv<<<dim3(NTOK / 256, CCONV), dim3(256), 0, stream>>>(xpt, conv_w, conv_b, xc);
    k_xdbl<<<dim3(NTOK / 256, 23), dim3(256), 0, stream>>>(xc, x_proj_w, dts, (__hip_bfloat16*)bc2);
    k_scan<<<dim3(BATCH * DSEQ), dim3(512), 0, stream>>>(xc, dts, (const unsigned short*)bc2,
                                                         dt_w, dt_b, A_logs, Ds, ybuf);
    k_tail<<<dim3(NTOK / 16), dim3(256), 0, stream>>>(ybuf, zbuf, (const float2*)wft,
                                                      ln_g, ln_b, (const float2*)wot, out);
}